// Round 1
// baseline (406.819 us; speedup 1.0000x reference)
//
#include <hip/hip_runtime.h>
#include <hip/hip_bf16.h>

#define B_  32
#define HW_ 4096
#define C_  256

using bf16x8 = __attribute__((ext_vector_type(8))) short;
using f32x4  = __attribute__((ext_vector_type(4))) float;

// round-to-nearest-even fp32 -> bf16 bits (no NaN handling; inputs are finite)
__device__ __forceinline__ ushort f2bf_rn(float x) {
    uint u = __builtin_bit_cast(uint, x);
    u += 0x7FFFu + ((u >> 16) & 1u);
    return (ushort)(u >> 16);
}
__device__ __forceinline__ float bfbits2f(ushort h) {
    uint u = ((uint)h) << 16;
    return __builtin_bit_cast(float, u);
}
__device__ __forceinline__ void split_bf16(float x, ushort& hi, ushort& lo) {
    hi = f2bf_rn(x);
    float hf = bfbits2f(hi);
    lo = f2bf_rn(x - hf);
}

// ---------------------------------------------------------------------------
// K1: scores[b,q,k] = sum_hw Q[b,hw,q] * K[b,hw,k], fp32-accurate via
// 3-term bf16 split (hi*hi + hi*lo + lo*hi). 128x128 tile, split-K=4,
// atomicAdd into fp32 scores buffer (pre-zeroed).
// grid: 512 = b(32) * tm(2) * tn(2) * s(4); block: 256 (4 waves, 2x2 of 64x64)
// ---------------------------------------------------------------------------
__global__ __launch_bounds__(256) void scores_kernel(const float* __restrict__ qg,
                                                     const float* __restrict__ kg,
                                                     float* __restrict__ scores) {
    int x  = blockIdx.x;
    int s  = x & 3;
    int tn = (x >> 2) & 1;
    int tm = (x >> 3) & 1;
    int b  = x >> 4;

    // LDS: [128 channels][32 hw], row stride 40 ushorts (80B) to dodge bank conflicts
    __shared__ ushort Qhi[128 * 40], Qlo[128 * 40], Khi[128 * 40], Klo[128 * 40];

    int tid  = threadIdx.x;
    int lane = tid & 63;
    int w    = tid >> 6;
    int m0   = (w >> 1) * 64;   // wave's q-offset within 128 tile
    int n0   = (w & 1) * 64;    // wave's k-offset within 128 tile
    int g    = lane >> 4;       // quarter-wave 0..3
    int r16  = lane & 15;

    f32x4 acc[4][4];
#pragma unroll
    for (int i = 0; i < 4; ++i)
#pragma unroll
        for (int j = 0; j < 4; ++j) acc[i][j] = (f32x4){0.f, 0.f, 0.f, 0.f};

    const float* qbase = qg + (size_t)b * HW_ * C_ + tm * 128;
    const float* kbase = kg + (size_t)b * HW_ * C_ + tn * 128;

    for (int ks = 0; ks < 32; ++ks) {
        int hw0 = s * 1024 + ks * 32;
        // ---- stage 32hw x 128c of Q and K, fp32 -> (hi,lo) bf16, transposed to [c][hw]
#pragma unroll
        for (int i = 0; i < 4; ++i) {
            int f   = i * 256 + tid;     // float4 index in 32x128 tile (1024 total)
            int hwl = f >> 5;            // 0..31
            int cb  = (f & 31) * 4;      // 0..124
            const float4 q4 = *reinterpret_cast<const float4*>(qbase + (size_t)(hw0 + hwl) * C_ + cb);
            const float4 k4 = *reinterpret_cast<const float4*>(kbase + (size_t)(hw0 + hwl) * C_ + cb);
            const float qa[4] = {q4.x, q4.y, q4.z, q4.w};
            const float ka[4] = {k4.x, k4.y, k4.z, k4.w};
#pragma unroll
            for (int u = 0; u < 4; ++u) {
                ushort hi, lo;
                split_bf16(qa[u], hi, lo);
                Qhi[(cb + u) * 40 + hwl] = hi;
                Qlo[(cb + u) * 40 + hwl] = lo;
                split_bf16(ka[u], hi, lo);
                Khi[(cb + u) * 40 + hwl] = hi;
                Klo[(cb + u) * 40 + hwl] = lo;
            }
        }
        __syncthreads();

        // ---- MFMA: A-frag and B-frag use the SAME (g,j)->hw mapping, so any
        // hardware k-permutation cancels in the contraction.
        bf16x8 ahi[4], alo[4];
#pragma unroll
        for (int mi = 0; mi < 4; ++mi) {
            int off = (m0 + mi * 16 + r16) * 40 + g * 8;
            ahi[mi] = *reinterpret_cast<const bf16x8*>(&Qhi[off]);
            alo[mi] = *reinterpret_cast<const bf16x8*>(&Qlo[off]);
        }
#pragma unroll
        for (int ni = 0; ni < 4; ++ni) {
            int off = (n0 + ni * 16 + r16) * 40 + g * 8;
            bf16x8 bhi = *reinterpret_cast<const bf16x8*>(&Khi[off]);
            bf16x8 blo = *reinterpret_cast<const bf16x8*>(&Klo[off]);
#pragma unroll
            for (int mi = 0; mi < 4; ++mi) {
                acc[mi][ni] = __builtin_amdgcn_mfma_f32_16x16x32_bf16(ahi[mi], bhi, acc[mi][ni], 0, 0, 0);
                acc[mi][ni] = __builtin_amdgcn_mfma_f32_16x16x32_bf16(ahi[mi], blo, acc[mi][ni], 0, 0, 0);
                acc[mi][ni] = __builtin_amdgcn_mfma_f32_16x16x32_bf16(alo[mi], bhi, acc[mi][ni], 0, 0, 0);
            }
        }
        __syncthreads();
    }

    // ---- epilogue: C/D layout col=lane&15, row=(lane>>4)*4+reg (m89-verified)
#pragma unroll
    for (int mi = 0; mi < 4; ++mi)
#pragma unroll
        for (int ni = 0; ni < 4; ++ni)
#pragma unroll
            for (int r = 0; r < 4; ++r) {
                int qrow = tm * 128 + m0 + mi * 16 + g * 4 + r;
                int kcol = tn * 128 + n0 + ni * 16 + r16;
                atomicAdd(&scores[((size_t)b * 256 + qrow) * 256 + kcol], acc[mi][ni][r]);
            }
}

// ---------------------------------------------------------------------------
// K2: row softmax over k (256), one wave per row; attn stored as bf16.
// grid: 2048, block: 256 (4 waves = 4 rows per block)
// ---------------------------------------------------------------------------
__global__ __launch_bounds__(256) void softmax_kernel(const float* __restrict__ scores,
                                                      ushort* __restrict__ attn) {
    int wid  = blockIdx.x * 4 + (threadIdx.x >> 6);  // global row 0..8191 (= b*256+q)
    int lane = threadIdx.x & 63;
    const float4 v = *reinterpret_cast<const float4*>(scores + (size_t)wid * 256 + lane * 4);
    float m = fmaxf(fmaxf(v.x, v.y), fmaxf(v.z, v.w));
#pragma unroll
    for (int off = 32; off; off >>= 1) m = fmaxf(m, __shfl_xor(m, off, 64));
    float e0 = __expf(v.x - m), e1 = __expf(v.y - m), e2 = __expf(v.z - m), e3 = __expf(v.w - m);
    float ssum = e0 + e1 + e2 + e3;
#pragma unroll
    for (int off = 32; off; off >>= 1) ssum += __shfl_xor(ssum, off, 64);
    float inv = 1.0f / ssum;
    ushort4 o;
    o.x = f2bf_rn(e0 * inv);
    o.y = f2bf_rn(e1 * inv);
    o.z = f2bf_rn(e2 * inv);
    o.w = f2bf_rn(e3 * inv);
    *reinterpret_cast<ushort4*>(attn + (size_t)wid * 256 + lane * 4) = o;
}

// ---------------------------------------------------------------------------
// K3: out[b,q,hw] = sum_k attn[b,q,k] * V[b,hw,k].  M=256(q) x N=64(hw) tile,
// K=256 in 8 steps of 32. A (attn, bf16, k-contiguous) and B (V fp32 ->bf16,
// k-contiguous) read straight from global with matching k-mapping.
// grid: 2048 = b(32) * hw-tile(64); block: 256 (4 waves, each 64q x 64hw)
// ---------------------------------------------------------------------------
__global__ __launch_bounds__(256) void pv_kernel(const ushort* __restrict__ attn,
                                                 const float* __restrict__ vg,
                                                 float* __restrict__ out) {
    int b   = blockIdx.x >> 6;
    int hw0 = (blockIdx.x & 63) * 64;
    int tid = threadIdx.x, lane = tid & 63, w = tid >> 6;
    int m0  = w * 64;
    int g   = lane >> 4, r16 = lane & 15;

    f32x4 acc[4][4];
#pragma unroll
    for (int i = 0; i < 4; ++i)
#pragma unroll
        for (int j = 0; j < 4; ++j) acc[i][j] = (f32x4){0.f, 0.f, 0.f, 0.f};

    for (int ks = 0; ks < 8; ++ks) {
        int k0 = ks * 32;
        bf16x8 a[4];
#pragma unroll
        for (int mi = 0; mi < 4; ++mi) {
            int qrow = m0 + mi * 16 + r16;
            a[mi] = *reinterpret_cast<const bf16x8*>(attn + ((size_t)b * 256 + qrow) * 256 + k0 + g * 8);
        }
#pragma unroll
        for (int ni = 0; ni < 4; ++ni) {
            int hw = hw0 + ni * 16 + r16;
            const float* vp = vg + ((size_t)(b * HW_ + hw)) * C_ + k0 + g * 8;
            const float4 v0 = *reinterpret_cast<const float4*>(vp);
            const float4 v1 = *reinterpret_cast<const float4*>(vp + 4);
            bf16x8 bf;
            short* bs = reinterpret_cast<short*>(&bf);
            bs[0] = (short)f2bf_rn(v0.x);
            bs[1] = (short)f2bf_rn(v0.y);
            bs[2] = (short)f2bf_rn(v0.z);
            bs[3] = (short)f2bf_rn(v0.w);
            bs[4] = (short)f2bf_rn(v1.x);
            bs[5] = (short)f2bf_rn(v1.y);
            bs[6] = (short)f2bf_rn(v1.z);
            bs[7] = (short)f2bf_rn(v1.w);
#pragma unroll
            for (int mi = 0; mi < 4; ++mi)
                acc[mi][ni] = __builtin_amdgcn_mfma_f32_16x16x32_bf16(a[mi], bf, acc[mi][ni], 0, 0, 0);
        }
    }

#pragma unroll
    for (int mi = 0; mi < 4; ++mi)
#pragma unroll
        for (int ni = 0; ni < 4; ++ni)
#pragma unroll
            for (int r = 0; r < 4; ++r) {
                int qrow = m0 + mi * 16 + g * 4 + r;
                int hw   = hw0 + ni * 16 + r16;
                out[((size_t)b * 256 + qrow) * 4096 + hw] = acc[mi][ni][r];
            }
}

extern "C" void kernel_launch(void* const* d_in, const int* in_sizes, int n_in,
                              void* d_out, int out_size, void* d_ws, size_t ws_size,
                              hipStream_t stream) {
    const float* q = (const float*)d_in[0];
    const float* k = (const float*)d_in[1];
    const float* v = (const float*)d_in[2];
    float* out = (float*)d_out;

    // workspace layout: [0, 8MiB) fp32 scores; [8MiB, 12MiB) bf16 attn
    float*  scores = (float*)d_ws;
    ushort* attn   = (ushort*)((char*)d_ws + (size_t)B_ * 256 * 256 * 4);

    hipMemsetAsync(d_ws, 0, (size_t)B_ * 256 * 256 * 4, stream);
    scores_kernel<<<512, 256, 0, stream>>>(q, k, scores);
    softmax_kernel<<<2048, 256, 0, stream>>>(scores, attn);
    pv_kernel<<<2048, 256, 0, stream>>>(attn, v, out);
}

// Round 3
// 245.491 us; speedup vs baseline: 1.6572x; 1.6572x over previous
//
#include <hip/hip_runtime.h>
#include <hip/hip_bf16.h>

#define B_  32
#define HW_ 4096
#define C_  256
#define S_LDS 40   // LDS row stride in ushorts: b128 reads conflict-free, b64 stores 2-way

using bf16x8 = __attribute__((ext_vector_type(8))) short;
using f32x4  = __attribute__((ext_vector_type(4))) float;

__device__ __forceinline__ ushort f2bf_rn(float x) {
    uint u = __builtin_bit_cast(uint, x);
    u += 0x7FFFu + ((u >> 16) & 1u);
    return (ushort)(u >> 16);
}

// pack two floats -> two bf16 (RN) in one u32 {low16 = a, high16 = b}
__device__ __forceinline__ uint pk_bf2(float a, float b) {
    return ((uint)f2bf_rn(b) << 16) | (uint)f2bf_rn(a);
}

// split pair into (hi, lo) bf16 pairs: x = hi + lo with ~17-bit effective mantissa
__device__ __forceinline__ void split2(float x0, float x1, uint& hi2, uint& lo2) {
    hi2 = pk_bf2(x0, x1);
    float h0 = __builtin_bit_cast(float, hi2 << 16);
    float h1 = __builtin_bit_cast(float, hi2 & 0xFFFF0000u);
    lo2 = pk_bf2(x0 - h0, x1 - h1);
}

// ---------------------------------------------------------------------------
// K1: scores[b,q,k] = sum_hw Q[b,hw,q]*K[b,hw,k] via 3-term bf16 split.
// Tile 128(q) x 64(k), split-K=4 (1024 hw per block), atomicAdd into fp32.
// grid 1024 = b(32, high bits for L3 locality) * tm(2) * tn(4) * s(4); block 256.
// ---------------------------------------------------------------------------
__global__ __launch_bounds__(256) void scores_kernel(const float* __restrict__ qg,
                                                     const float* __restrict__ kg,
                                                     float* __restrict__ scores) {
    int x  = blockIdx.x;
    int s  = x & 3;
    int tn = (x >> 2) & 3;
    int tm = (x >> 4) & 1;
    int b  = x >> 5;

    __shared__ ushort Qhi[128 * S_LDS], Qlo[128 * S_LDS];
    __shared__ ushort Khi[64 * S_LDS],  Klo[64 * S_LDS];

    int tid = threadIdx.x, lane = tid & 63, w = tid >> 6;
    int m0 = (w >> 1) * 64;     // wave q-offset (2x2 wave grid over 128x64)
    int n0 = (w & 1) * 32;      // wave k-offset
    int g = lane >> 4, r16 = lane & 15;

    int cq = tid & 127;          // staging: q-channel owned by this thread
    int hq = (tid >> 7) * 16;    // 16 hw values
    int ck = tid & 63;           // staging: k-channel
    int hk = (tid >> 6) * 8;     // 8 hw values

    const float* qcol = qg + (size_t)b * HW_ * C_ + tm * 128 + cq;
    const float* kcol = kg + (size_t)b * HW_ * C_ + tn * 64 + ck;

    f32x4 acc[4][2];
#pragma unroll
    for (int i = 0; i < 4; ++i)
#pragma unroll
        for (int j = 0; j < 2; ++j) acc[i][j] = (f32x4){0.f, 0.f, 0.f, 0.f};

    for (int it = 0; it < 32; ++it) {
        int hw0 = s * 1024 + it * 32;

        // ---- Q staging: thread stages channel cq, hw [hq, hq+16)
        {
            const float* qp = qcol + (size_t)(hw0 + hq) * C_;
#pragma unroll
            for (int half = 0; half < 2; ++half) {
                float v[8];
#pragma unroll
                for (int j = 0; j < 8; ++j) v[j] = qp[(size_t)(half * 8 + j) * C_];
                uint hi2[4], lo2[4];
#pragma unroll
                for (int jp = 0; jp < 4; ++jp) split2(v[2 * jp], v[2 * jp + 1], hi2[jp], lo2[jp]);
                int base = cq * S_LDS + hq + half * 8;
                *reinterpret_cast<uint2*>(&Qhi[base])     = make_uint2(hi2[0], hi2[1]);
                *reinterpret_cast<uint2*>(&Qhi[base + 4]) = make_uint2(hi2[2], hi2[3]);
                *reinterpret_cast<uint2*>(&Qlo[base])     = make_uint2(lo2[0], lo2[1]);
                *reinterpret_cast<uint2*>(&Qlo[base + 4]) = make_uint2(lo2[2], lo2[3]);
            }
        }
        // ---- K staging: thread stages channel ck, hw [hk, hk+8)
        {
            const float* kp = kcol + (size_t)(hw0 + hk) * C_;
            float v[8];
#pragma unroll
            for (int j = 0; j < 8; ++j) v[j] = kp[(size_t)j * C_];
            uint hi2[4], lo2[4];
#pragma unroll
            for (int jp = 0; jp < 4; ++jp) split2(v[2 * jp], v[2 * jp + 1], hi2[jp], lo2[jp]);
            int base = ck * S_LDS + hk;
            *reinterpret_cast<uint2*>(&Khi[base])     = make_uint2(hi2[0], hi2[1]);
            *reinterpret_cast<uint2*>(&Khi[base + 4]) = make_uint2(hi2[2], hi2[3]);
            *reinterpret_cast<uint2*>(&Klo[base])     = make_uint2(lo2[0], lo2[1]);
            *reinterpret_cast<uint2*>(&Klo[base + 4]) = make_uint2(lo2[2], lo2[3]);
        }
        __syncthreads();

        // ---- MFMA: same (g,j)->hw mapping for A and B frags => k-permutation cancels
        bf16x8 ahi[4], alo[4];
#pragma unroll
        for (int mi = 0; mi < 4; ++mi) {
            int off = (m0 + mi * 16 + r16) * S_LDS + g * 8;
            ahi[mi] = *reinterpret_cast<const bf16x8*>(&Qhi[off]);
            alo[mi] = *reinterpret_cast<const bf16x8*>(&Qlo[off]);
        }
#pragma unroll
        for (int ni = 0; ni < 2; ++ni) {
            int off = (n0 + ni * 16 + r16) * S_LDS + g * 8;
            bf16x8 bhi = *reinterpret_cast<const bf16x8*>(&Khi[off]);
            bf16x8 blo = *reinterpret_cast<const bf16x8*>(&Klo[off]);
#pragma unroll
            for (int mi = 0; mi < 4; ++mi) {
                acc[mi][ni] = __builtin_amdgcn_mfma_f32_16x16x32_bf16(ahi[mi], bhi, acc[mi][ni], 0, 0, 0);
                acc[mi][ni] = __builtin_amdgcn_mfma_f32_16x16x32_bf16(ahi[mi], blo, acc[mi][ni], 0, 0, 0);
                acc[mi][ni] = __builtin_amdgcn_mfma_f32_16x16x32_bf16(alo[mi], bhi, acc[mi][ni], 0, 0, 0);
            }
        }
        __syncthreads();
    }

    // ---- epilogue: C/D layout col=lane&15, row=(lane>>4)*4+reg (m89-verified)
#pragma unroll
    for (int mi = 0; mi < 4; ++mi)
#pragma unroll
        for (int ni = 0; ni < 2; ++ni)
#pragma unroll
            for (int r = 0; r < 4; ++r) {
                int qrow = tm * 128 + m0 + mi * 16 + g * 4 + r;
                int kc   = tn * 64 + n0 + ni * 16 + r16;
                atomicAdd(&scores[((size_t)b * 256 + qrow) * 256 + kc], acc[mi][ni][r]);
            }
}

// ---------------------------------------------------------------------------
// K2: row softmax over k (256), one wave per row; attn stored as bf16.
// ---------------------------------------------------------------------------
__global__ __launch_bounds__(256) void softmax_kernel(const float* __restrict__ scores,
                                                      ushort* __restrict__ attn) {
    int wid  = blockIdx.x * 4 + (threadIdx.x >> 6);
    int lane = threadIdx.x & 63;
    const float4 v = *reinterpret_cast<const float4*>(scores + (size_t)wid * 256 + lane * 4);
    float m = fmaxf(fmaxf(v.x, v.y), fmaxf(v.z, v.w));
#pragma unroll
    for (int off = 32; off; off >>= 1) m = fmaxf(m, __shfl_xor(m, off, 64));
    float e0 = __expf(v.x - m), e1 = __expf(v.y - m), e2 = __expf(v.z - m), e3 = __expf(v.w - m);
    float ssum = e0 + e1 + e2 + e3;
#pragma unroll
    for (int off = 32; off; off >>= 1) ssum += __shfl_xor(ssum, off, 64);
    float inv = 1.0f / ssum;
    uint2 o;
    o.x = pk_bf2(e0 * inv, e1 * inv);
    o.y = pk_bf2(e2 * inv, e3 * inv);
    *reinterpret_cast<uint2*>(attn + (size_t)wid * 256 + lane * 4) = o;
}

// ---------------------------------------------------------------------------
// K3: out[b,q,hw] = sum_k attn[b,q,k] * V[b,hw,k].  M=256 x N=64 tile, K=256.
// ---------------------------------------------------------------------------
__global__ __launch_bounds__(256) void pv_kernel(const ushort* __restrict__ attn,
                                                 const float* __restrict__ vg,
                                                 float* __restrict__ out) {
    int b   = blockIdx.x >> 6;
    int hw0 = (blockIdx.x & 63) * 64;
    int tid = threadIdx.x, lane = tid & 63, w = tid >> 6;
    int m0  = w * 64;
    int g   = lane >> 4, r16 = lane & 15;

    f32x4 acc[4][4];
#pragma unroll
    for (int i = 0; i < 4; ++i)
#pragma unroll
        for (int j = 0; j < 4; ++j) acc[i][j] = (f32x4){0.f, 0.f, 0.f, 0.f};

    for (int ks = 0; ks < 8; ++ks) {
        int k0 = ks * 32;
        bf16x8 a[4];
#pragma unroll
        for (int mi = 0; mi < 4; ++mi) {
            int qrow = m0 + mi * 16 + r16;
            a[mi] = *reinterpret_cast<const bf16x8*>(attn + ((size_t)b * 256 + qrow) * 256 + k0 + g * 8);
        }
#pragma unroll
        for (int ni = 0; ni < 4; ++ni) {
            int hw = hw0 + ni * 16 + r16;
            const float* vp = vg + ((size_t)(b * HW_ + hw)) * C_ + k0 + g * 8;
            const float4 v0 = *reinterpret_cast<const float4*>(vp);
            const float4 v1 = *reinterpret_cast<const float4*>(vp + 4);
            bf16x8 bf;
            uint* bu = reinterpret_cast<uint*>(&bf);
            bu[0] = pk_bf2(v0.x, v0.y);
            bu[1] = pk_bf2(v0.z, v0.w);
            bu[2] = pk_bf2(v1.x, v1.y);
            bu[3] = pk_bf2(v1.z, v1.w);
#pragma unroll
            for (int mi = 0; mi < 4; ++mi)
                acc[mi][ni] = __builtin_amdgcn_mfma_f32_16x16x32_bf16(a[mi], bf, acc[mi][ni], 0, 0, 0);
        }
    }

#pragma unroll
    for (int mi = 0; mi < 4; ++mi)
#pragma unroll
        for (int ni = 0; ni < 4; ++ni)
#pragma unroll
            for (int r = 0; r < 4; ++r) {
                int qrow = m0 + mi * 16 + g * 4 + r;
                int hw   = hw0 + ni * 16 + r16;
                out[((size_t)b * 256 + qrow) * 4096 + hw] = acc[mi][ni][r];
            }
}

extern "C" void kernel_launch(void* const* d_in, const int* in_sizes, int n_in,
                              void* d_out, int out_size, void* d_ws, size_t ws_size,
                              hipStream_t stream) {
    const float* q = (const float*)d_in[0];
    const float* k = (const float*)d_in[1];
    const float* v = (const float*)d_in[2];
    float* out = (float*)d_out;

    float*  scores = (float*)d_ws;
    ushort* attn   = (ushort*)((char*)d_ws + (size_t)B_ * 256 * 256 * 4);

    (void)hipMemsetAsync(d_ws, 0, (size_t)B_ * 256 * 256 * 4, stream);
    scores_kernel<<<1024, 256, 0, stream>>>(q, k, scores);
    softmax_kernel<<<2048, 256, 0, stream>>>(scores, attn);
    pv_kernel<<<2048, 256, 0, stream>>>(attn, v, out);
}

// Round 4
// 215.252 us; speedup vs baseline: 1.8900x; 1.1405x over previous
//
#include <hip/hip_runtime.h>
#include <hip/hip_bf16.h>

#define B_  32
#define HW_ 4096
#define C_  256
#define S_LDS 40   // LDS row stride in ushorts (80B): 16B-aligned rows, b128 r/w <=2-way banks

using bf16x8 = __attribute__((ext_vector_type(8))) short;
using f32x4  = __attribute__((ext_vector_type(4))) float;

__device__ __forceinline__ ushort f2bf_rn(float x) {
    uint u = __builtin_bit_cast(uint, x);
    u += 0x7FFFu + ((u >> 16) & 1u);
    return (ushort)(u >> 16);
}
__device__ __forceinline__ uint pk_bf2(float a, float b) {   // RN pack (K2 only)
    return ((uint)f2bf_rn(b) << 16) | (uint)f2bf_rn(a);
}
// 1-instr RTZ pack of two floats' top-16 bits: {bf16_rtz(x1), bf16_rtz(x0)}
__device__ __forceinline__ uint pk_rtz(float x0, float x1) {
    return __builtin_amdgcn_perm(__builtin_bit_cast(uint, x1),
                                 __builtin_bit_cast(uint, x0), 0x07060302u);
}
// RTZ split: x = hi + lo, hi = truncate-to-bf16, |lo| <= 2^-8|x|
__device__ __forceinline__ void split2_rtz(float x0, float x1, uint& hi2, uint& lo2) {
    uint u0 = __builtin_bit_cast(uint, x0), u1 = __builtin_bit_cast(uint, x1);
    hi2 = __builtin_amdgcn_perm(u1, u0, 0x07060302u);
    float h0 = __builtin_bit_cast(float, u0 & 0xFFFF0000u);
    float h1 = __builtin_bit_cast(float, u1 & 0xFFFF0000u);
    lo2 = pk_rtz(x0 - h0, x1 - h1);
}

// ---------------------------------------------------------------------------
// K1: scores[b,q,k] = sum_hw Q[b,hw,q]*K[b,hw,k] via 3-term bf16 RTZ split.
// Tile 128(q) x 64(k), split-K=4. Register-double-buffered staging pipeline:
// iteration t+1's global loads are issued before converting/storing t, so
// HBM/L2 latency hides under convert+MFMA (counted-vmcnt, compiler-emitted).
// grid 1024 = b(32) * tm(2) * tn(4) * s(4); block 256 (4 waves, 2x2 of 64x32).
// ---------------------------------------------------------------------------
__global__ __launch_bounds__(256) void scores_kernel(const float* __restrict__ qg,
                                                     const float* __restrict__ kg,
                                                     float* __restrict__ scores) {
    int x  = blockIdx.x;
    int s  = x & 3;
    int tn = (x >> 2) & 3;
    int tm = (x >> 4) & 1;
    int b  = x >> 5;

    __shared__ __align__(16) ushort Qhi[128 * S_LDS], Qlo[128 * S_LDS];
    __shared__ __align__(16) ushort Khi[64 * S_LDS],  Klo[64 * S_LDS];

    int tid = threadIdx.x, lane = tid & 63, w = tid >> 6;
    int m0 = (w >> 1) * 64;
    int n0 = (w & 1) * 32;
    int g = lane >> 4, r16 = lane & 15;

    int cq = tid & 127;          // staging: q-channel owned by this thread
    int hq = (tid >> 7) * 16;    // 16 hw values
    int ck = tid & 63;           // staging: k-channel
    int hk = (tid >> 6) * 8;     // 8 hw values

    const float* qcol = qg + (size_t)b * HW_ * C_ + tm * 128 + cq;
    const float* kcol = kg + (size_t)b * HW_ * C_ + tn * 64 + ck;

    f32x4 acc[4][2];
#pragma unroll
    for (int i = 0; i < 4; ++i)
#pragma unroll
        for (int j = 0; j < 2; ++j) acc[i][j] = (f32x4){0.f, 0.f, 0.f, 0.f};

#define LOAD_QK(qr, kr, itv) {                                                 \
        int hw0 = s * 1024 + (itv) * 32;                                       \
        const float* qp = qcol + (size_t)(hw0 + hq) * C_;                      \
        _Pragma("unroll")                                                      \
        for (int j = 0; j < 16; ++j) qr[j] = qp[(size_t)j * C_];               \
        const float* kp = kcol + (size_t)(hw0 + hk) * C_;                      \
        _Pragma("unroll")                                                      \
        for (int j = 0; j < 8; ++j) kr[j] = kp[(size_t)j * C_];                \
    }

#define CONVERT_STORE(qr, kr) {                                                \
        uint qh[8], ql[8];                                                     \
        _Pragma("unroll")                                                      \
        for (int p = 0; p < 8; ++p) split2_rtz(qr[2*p], qr[2*p+1], qh[p], ql[p]); \
        int qb_ = cq * S_LDS + hq;                                             \
        *reinterpret_cast<uint4*>(&Qhi[qb_])     = make_uint4(qh[0], qh[1], qh[2], qh[3]); \
        *reinterpret_cast<uint4*>(&Qhi[qb_ + 8]) = make_uint4(qh[4], qh[5], qh[6], qh[7]); \
        *reinterpret_cast<uint4*>(&Qlo[qb_])     = make_uint4(ql[0], ql[1], ql[2], ql[3]); \
        *reinterpret_cast<uint4*>(&Qlo[qb_ + 8]) = make_uint4(ql[4], ql[5], ql[6], ql[7]); \
        uint kh[4], kl[4];                                                     \
        _Pragma("unroll")                                                      \
        for (int p = 0; p < 4; ++p) split2_rtz(kr[2*p], kr[2*p+1], kh[p], kl[p]); \
        int kb_ = ck * S_LDS + hk;                                             \
        *reinterpret_cast<uint4*>(&Khi[kb_]) = make_uint4(kh[0], kh[1], kh[2], kh[3]); \
        *reinterpret_cast<uint4*>(&Klo[kb_]) = make_uint4(kl[0], kl[1], kl[2], kl[3]); \
    }

#define MFMA_PHASE() {                                                         \
        bf16x8 ahi[4], alo[4];                                                 \
        _Pragma("unroll")                                                      \
        for (int mi = 0; mi < 4; ++mi) {                                       \
            int off = (m0 + mi * 16 + r16) * S_LDS + g * 8;                    \
            ahi[mi] = *reinterpret_cast<const bf16x8*>(&Qhi[off]);             \
            alo[mi] = *reinterpret_cast<const bf16x8*>(&Qlo[off]);             \
        }                                                                      \
        _Pragma("unroll")                                                      \
        for (int ni = 0; ni < 2; ++ni) {                                       \
            int off = (n0 + ni * 16 + r16) * S_LDS + g * 8;                    \
            bf16x8 bhi = *reinterpret_cast<const bf16x8*>(&Khi[off]);          \
            bf16x8 blo = *reinterpret_cast<const bf16x8*>(&Klo[off]);          \
            _Pragma("unroll")                                                  \
            for (int mi = 0; mi < 4; ++mi) {                                   \
                acc[mi][ni] = __builtin_amdgcn_mfma_f32_16x16x32_bf16(ahi[mi], bhi, acc[mi][ni], 0, 0, 0); \
                acc[mi][ni] = __builtin_amdgcn_mfma_f32_16x16x32_bf16(ahi[mi], blo, acc[mi][ni], 0, 0, 0); \
                acc[mi][ni] = __builtin_amdgcn_mfma_f32_16x16x32_bf16(alo[mi], bhi, acc[mi][ni], 0, 0, 0); \
            }                                                                  \
        }                                                                      \
    }

#define STEP(qc, kc, qn, kn, itv, doload) {                                    \
        if (doload) LOAD_QK(qn, kn, (itv) + 1);                                \
        __syncthreads();                                                       \
        CONVERT_STORE(qc, kc);                                                 \
        __syncthreads();                                                       \
        MFMA_PHASE();                                                          \
    }

    float qa[16], ka[8], qb[16], kb[8];
    LOAD_QK(qa, ka, 0);
    for (int p = 0; p < 16; ++p) {
        STEP(qa, ka, qb, kb, 2 * p, true);         // prefetch 2p+1 (<=31 always)
        STEP(qb, kb, qa, ka, 2 * p + 1, p < 15);   // prefetch 2p+2 unless last
    }

#pragma unroll
    for (int mi = 0; mi < 4; ++mi)
#pragma unroll
        for (int ni = 0; ni < 2; ++ni)
#pragma unroll
            for (int r = 0; r < 4; ++r) {
                int qrow = tm * 128 + m0 + mi * 16 + g * 4 + r;
                int kc   = tn * 64 + n0 + ni * 16 + r16;
                atomicAdd(&scores[((size_t)b * 256 + qrow) * 256 + kc], acc[mi][ni][r]);
            }
#undef STEP
#undef MFMA_PHASE
#undef CONVERT_STORE
#undef LOAD_QK
}

// ---------------------------------------------------------------------------
// K2: row softmax over k (256), one wave per row; attn stored as bf16 (RN).
// ---------------------------------------------------------------------------
__global__ __launch_bounds__(256) void softmax_kernel(const float* __restrict__ scores,
                                                      ushort* __restrict__ attn) {
    int wid  = blockIdx.x * 4 + (threadIdx.x >> 6);
    int lane = threadIdx.x & 63;
    const float4 v = *reinterpret_cast<const float4*>(scores + (size_t)wid * 256 + lane * 4);
    float m = fmaxf(fmaxf(v.x, v.y), fmaxf(v.z, v.w));
#pragma unroll
    for (int off = 32; off; off >>= 1) m = fmaxf(m, __shfl_xor(m, off, 64));
    float e0 = __expf(v.x - m), e1 = __expf(v.y - m), e2 = __expf(v.z - m), e3 = __expf(v.w - m);
    float ssum = e0 + e1 + e2 + e3;
#pragma unroll
    for (int off = 32; off; off >>= 1) ssum += __shfl_xor(ssum, off, 64);
    float inv = 1.0f / ssum;
    uint2 o;
    o.x = pk_bf2(e0 * inv, e1 * inv);
    o.y = pk_bf2(e2 * inv, e3 * inv);
    *reinterpret_cast<uint2*>(attn + (size_t)wid * 256 + lane * 4) = o;
}

// ---------------------------------------------------------------------------
// K3: out[b,q,hw] = sum_k attn[b,q,k] * V[b,hw,k].  M=256 x N=64 tile, K=256.
// V packed fp32->bf16 via 1-instr v_perm RTZ.
// ---------------------------------------------------------------------------
__global__ __launch_bounds__(256) void pv_kernel(const ushort* __restrict__ attn,
                                                 const float* __restrict__ vg,
                                                 float* __restrict__ out) {
    int b   = blockIdx.x >> 6;
    int hw0 = (blockIdx.x & 63) * 64;
    int tid = threadIdx.x, lane = tid & 63, w = tid >> 6;
    int m0  = w * 64;
    int g   = lane >> 4, r16 = lane & 15;

    f32x4 acc[4][4];
#pragma unroll
    for (int i = 0; i < 4; ++i)
#pragma unroll
        for (int j = 0; j < 4; ++j) acc[i][j] = (f32x4){0.f, 0.f, 0.f, 0.f};

    for (int ks = 0; ks < 8; ++ks) {
        int k0 = ks * 32;
        bf16x8 a[4];
#pragma unroll
        for (int mi = 0; mi < 4; ++mi) {
            int qrow = m0 + mi * 16 + r16;
            a[mi] = *reinterpret_cast<const bf16x8*>(attn + ((size_t)b * 256 + qrow) * 256 + k0 + g * 8);
        }
        float4 vv[4][2];
#pragma unroll
        for (int ni = 0; ni < 4; ++ni) {
            int hw = hw0 + ni * 16 + r16;
            const float* vp = vg + ((size_t)(b * HW_ + hw)) * C_ + k0 + g * 8;
            vv[ni][0] = *reinterpret_cast<const float4*>(vp);
            vv[ni][1] = *reinterpret_cast<const float4*>(vp + 4);
        }
#pragma unroll
        for (int ni = 0; ni < 4; ++ni) {
            bf16x8 bf;
            uint* bu = reinterpret_cast<uint*>(&bf);
            bu[0] = pk_rtz(vv[ni][0].x, vv[ni][0].y);
            bu[1] = pk_rtz(vv[ni][0].z, vv[ni][0].w);
            bu[2] = pk_rtz(vv[ni][1].x, vv[ni][1].y);
            bu[3] = pk_rtz(vv[ni][1].z, vv[ni][1].w);
#pragma unroll
            for (int mi = 0; mi < 4; ++mi)
                acc[mi][ni] = __builtin_amdgcn_mfma_f32_16x16x32_bf16(a[mi], bf, acc[mi][ni], 0, 0, 0);
        }
    }

#pragma unroll
    for (int mi = 0; mi < 4; ++mi)
#pragma unroll
        for (int ni = 0; ni < 4; ++ni)
#pragma unroll
            for (int r = 0; r < 4; ++r) {
                int qrow = m0 + mi * 16 + g * 4 + r;
                int hw   = hw0 + ni * 16 + r16;
                out[((size_t)b * 256 + qrow) * 4096 + hw] = acc[mi][ni][r];
            }
}

extern "C" void kernel_launch(void* const* d_in, const int* in_sizes, int n_in,
                              void* d_out, int out_size, void* d_ws, size_t ws_size,
                              hipStream_t stream) {
    const float* q = (const float*)d_in[0];
    const float* k = (const float*)d_in[1];
    const float* v = (const float*)d_in[2];
    float* out = (float*)d_out;

    float*  scores = (float*)d_ws;
    ushort* attn   = (ushort*)((char*)d_ws + (size_t)B_ * 256 * 256 * 4);

    (void)hipMemsetAsync(d_ws, 0, (size_t)B_ * 256 * 256 * 4, stream);
    scores_kernel<<<1024, 256, 0, stream>>>(q, k, scores);
    softmax_kernel<<<2048, 256, 0, stream>>>(scores, attn);
    pv_kernel<<<2048, 256, 0, stream>>>(attn, v, out);
}